// Round 4
// baseline (9570.787 us; speedup 1.0000x reference)
//
#include <hip/hip_runtime.h>
#include <hip/hip_bf16.h>
#include <math.h>

#define TSTEPS 512
#define NEX 256
#define NIN 128
#define HDIM 256
#define NCOLS 16          // example-columns (16 examples each)
#define NROWBLK 16        // unit-tile blocks per column

typedef __attribute__((ext_vector_type(8))) short short8;   // 8 bf16 (MFMA A/B frag)
typedef __attribute__((ext_vector_type(4))) float f32x4;    // MFMA C/D frag

__device__ __forceinline__ float sig_(float x) {
    return __builtin_amdgcn_rcpf(1.0f + __builtin_amdgcn_exp2f(-1.44269504f * x));
}
__device__ __forceinline__ float tanh_(float x) {
    return 1.0f - 2.0f * __builtin_amdgcn_rcpf(1.0f + __builtin_amdgcn_exp2f(2.88539008f * x));
}

__global__ void zero_flags(int* flags, int n) {
    int i = blockIdx.x * blockDim.x + threadIdx.x;
    if (i < n) flags[i] = 0;
}

// Persistent LSTM, 1-wave blocks. 256 blocks = 16 unit-tiles x 16 example-columns.
// Block b: i=b>>4 -> u0=i*16 (units), j=b&15 -> e0=j*16 (examples). 64 threads = 1 wave.
// Per step, the wave computes D[16u x 16ex] for 4 gates via mfma(W_frag, Z_frag):
// lane l -> (ex = e0 + (l&15), units = u0 + (l>>4)*4 + r). Weights held in VGPRs.
// h exchanged as packed bf16 through d_ws (parity double buffer) with agent atomics;
// per-(t,column) flag counters gate the recurrence. A,C are plain cached stores.
__global__ __launch_bounds__(64, 1) void lstm_persist(
    const float* __restrict__ X,     // [256,128,512]
    const float* __restrict__ Wih,   // [1024,128]
    const float* __restrict__ Whh,   // [1024,256]
    const float* __restrict__ bias,  // [1024]
    float* __restrict__ A,           // [512,256,256]
    float* __restrict__ C,           // [512,256,256]
    int* __restrict__ flags,         // [512*16]
    unsigned int* __restrict__ hbuf) // [2][256][128] u32 (bf16 pairs)
{
    // Row stride 392 bf16 = 784 B: 16B-aligned rows (784 = 49*16), bank-spread (196%32=4).
    __shared__ __align__(16) __hip_bfloat16 Ws[4][16][392]; // one-time staging target, 50.2 KB
    __shared__ __align__(16) __hip_bfloat16 Zs[16][392];    // [ex_local][ h(256)|x(128) ] 12.5 KB

    const int tid = threadIdx.x;
    const int b = blockIdx.x;
    const int i = b >> 4, j = b & 15;
    const int u0 = i * 16, e0 = j * 16;

    // ---- one-time weight staging: fp32 -> bf16 in LDS, [gate][unit_local][k] ----
    for (int idx = tid; idx < 64 * 96; idx += 64) {   // 64 rows x 96 float4 (64 Whh + 32 Wih)
        const int row = idx / 96, q = idx - row * 96;
        const int g = row >> 4, ul = row & 15;
        float4 v;
        int k0;
        if (q < 64) {
            v = *(const float4*)(Whh + (size_t)(g * HDIM + u0 + ul) * HDIM + 4 * q);
            k0 = 4 * q;
        } else {
            v = *(const float4*)(Wih + (size_t)(g * HDIM + u0 + ul) * NIN + 4 * (q - 64));
            k0 = HDIM + 4 * (q - 64);
        }
        Ws[g][ul][k0 + 0] = (__hip_bfloat16)v.x;
        Ws[g][ul][k0 + 1] = (__hip_bfloat16)v.y;
        Ws[g][ul][k0 + 2] = (__hip_bfloat16)v.z;
        Ws[g][ul][k0 + 3] = (__hip_bfloat16)v.w;
    }
    __syncthreads();

    const int mrow = tid & 15;          // frag row; D: col -> ex_local
    const int kg   = tid >> 4;          // k-group; D: rows (kg*4+r) -> unit_local
    const int ex   = e0 + mrow;
    const int ub   = u0 + kg * 4;       // this lane's first unit

    // ---- W fragments -> registers (loop-invariant): 4 gates x 12 k-chunks ----
    short8 wf0[12], wf1[12], wf2[12], wf3[12];
#pragma unroll
    for (int kk = 0; kk < 12; ++kk) {
        wf0[kk] = *(const short8*)&Ws[0][mrow][kk * 32 + kg * 8];
        wf1[kk] = *(const short8*)&Ws[1][mrow][kk * 32 + kg * 8];
        wf2[kk] = *(const short8*)&Ws[2][mrow][kk * 32 + kg * 8];
        wf3[kk] = *(const short8*)&Ws[3][mrow][kk * 32 + kg * 8];
    }
    // ---- bias -> registers: 2*b for my 4 units x 4 gates ----
    float bsr[4][4];
#pragma unroll
    for (int g = 0; g < 4; ++g)
#pragma unroll
        for (int r = 0; r < 4; ++r)
            bsr[g][r] = 2.0f * bias[g * HDIM + ub + r];

    float cr[4] = {0.f, 0.f, 0.f, 0.f};

    for (int t = 0; t < TSTEPS; ++t) {
        // ---- stage x[t] (recurrence-independent; overlaps the spin) ----
#pragma unroll
        for (int s = 0; s < 32; ++s) {
            const int idx = s * 64 + tid;           // 2048 = 16 ex x 128 inputs
            const int exl = idx >> 7, ii = idx & 127;
            const float xv = X[((size_t)(e0 + exl) * NIN + ii) * TSTEPS + t];
            Zs[exl][HDIM + ii] = (__hip_bfloat16)xv;
        }

        // ---- wait for h[t-1], then pull packed bf16 h into Zs ----
        if (t > 0) {
            const int* f = &flags[(t - 1) * NCOLS + j];
            while (__hip_atomic_load(f, __ATOMIC_ACQUIRE, __HIP_MEMORY_SCOPE_AGENT) < NROWBLK) {}
            const unsigned int* src = hbuf + (size_t)((t - 1) & 1) * NEX * 128 + (size_t)e0 * 128;
#pragma unroll
            for (int s = 0; s < 32; ++s) {
                const int idx = s * 64 + tid;       // 2048 u32 = 16 ex x 128
                const int exl = idx >> 7, q = idx & 127;
                const unsigned int v = __hip_atomic_load(src + exl * 128 + q,
                                                         __ATOMIC_RELAXED, __HIP_MEMORY_SCOPE_AGENT);
                ((unsigned int*)&Zs[exl][0])[q] = v;
            }
        } else {
#pragma unroll
            for (int s = 0; s < 32; ++s) {
                const int idx = s * 64 + tid;
                const int exl = idx >> 7, q = idx & 127;
                ((unsigned int*)&Zs[exl][0])[q] = 0u;
            }
        }

        // ---- gate GEMM: D[16u x 16ex] per gate, K=384 (compiler inserts lgkmcnt) ----
        f32x4 a0 = {0.f, 0.f, 0.f, 0.f}, a1 = a0, a2 = a0, a3 = a0;
#pragma unroll
        for (int kk = 0; kk < 12; ++kk) {
            const short8 zf = *(const short8*)&Zs[mrow][kk * 32 + kg * 8];
            a0 = __builtin_amdgcn_mfma_f32_16x16x32_bf16(wf0[kk], zf, a0, 0, 0, 0);
            a1 = __builtin_amdgcn_mfma_f32_16x16x32_bf16(wf1[kk], zf, a1, 0, 0, 0);
            a2 = __builtin_amdgcn_mfma_f32_16x16x32_bf16(wf2[kk], zf, a2, 0, 0, 0);
            a3 = __builtin_amdgcn_mfma_f32_16x16x32_bf16(wf3[kk], zf, a3, 0, 0, 0);
        }

        // ---- pointwise cell (register-local): r -> unit ub+r, ex fixed ----
        float hr[4];
#pragma unroll
        for (int r = 0; r < 4; ++r) {
            const float gi = sig_(a0[r] + bsr[0][r]);
            const float gf = sig_(a1[r] + bsr[1][r]);
            const float gg = tanh_(a2[r] + bsr[2][r]);
            const float go = sig_(a3[r] + bsr[3][r]);
            cr[r] = gf * cr[r] + gi * gg;
            hr[r] = go * tanh_(cr[r]);
        }

        // ---- stores: fp32 outputs (plain, cached) + packed bf16 exchange (agent) ----
        const size_t off = (size_t)t * NEX * HDIM + (size_t)ex * HDIM + ub;
        *(float4*)&A[off] = make_float4(hr[0], hr[1], hr[2], hr[3]);
        *(float4*)&C[off] = make_float4(cr[0], cr[1], cr[2], cr[3]);

        __hip_bfloat162 p01(__float2bfloat16(hr[0]), __float2bfloat16(hr[1]));
        __hip_bfloat162 p23(__float2bfloat16(hr[2]), __float2bfloat16(hr[3]));
        unsigned int* dst = hbuf + (size_t)(t & 1) * NEX * 128 + (size_t)ex * 128 + (ub >> 1);
        __hip_atomic_store(dst + 0, *(unsigned int*)&p01, __ATOMIC_RELAXED, __HIP_MEMORY_SCOPE_AGENT);
        __hip_atomic_store(dst + 1, *(unsigned int*)&p23, __ATOMIC_RELAXED, __HIP_MEMORY_SCOPE_AGENT);

        asm volatile("s_waitcnt vmcnt(0)" ::: "memory");
        if (tid == 0) {
            __hip_atomic_fetch_add(&flags[t * NCOLS + j], 1,
                                   __ATOMIC_RELEASE, __HIP_MEMORY_SCOPE_AGENT);
        }
    }
}

extern "C" void kernel_launch(void* const* d_in, const int* in_sizes, int n_in,
                              void* d_out, int out_size, void* d_ws, size_t ws_size,
                              hipStream_t stream) {
    const float* X   = (const float*)d_in[0];  // [256,128,512]
    const float* Wih = (const float*)d_in[1];  // [1024,128]
    const float* Whh = (const float*)d_in[2];  // [1024,256]
    const float* b   = (const float*)d_in[3];  // [1024]
    float* A = (float*)d_out;                           // [512,256,256]
    float* C = A + (size_t)TSTEPS * NEX * HDIM;         // [512,256,256]

    int* flags = (int*)d_ws;                            // [512*16] ints = 32 KB
    unsigned int* hbuf = (unsigned int*)((char*)d_ws + (size_t)TSTEPS * NCOLS * sizeof(int));
                                                        // [2][256][128] u32 = 256 KB

    const int nflags = TSTEPS * NCOLS;
    zero_flags<<<(nflags + 255) / 256, 256, 0, stream>>>(flags, nflags);

    void* args[] = {(void*)&X, (void*)&Wih, (void*)&Whh, (void*)&b,
                    (void*)&A, (void*)&C, (void*)&flags, (void*)&hbuf};
    hipError_t err = hipLaunchCooperativeKernel((const void*)lstm_persist,
                                                dim3(256), dim3(64), args, 0, stream);
    if (err != hipSuccess) {
        lstm_persist<<<dim3(256), dim3(64), 0, stream>>>(X, Wih, Whh, b, A, C, flags, hbuf);
    }
}

// Round 5
// 3633.209 us; speedup vs baseline: 2.6343x; 2.6343x over previous
//
#include <hip/hip_runtime.h>
#include <hip/hip_bf16.h>

#define TSTEPS 512
#define NEX 256
#define NIN 128
#define HDIM 256
#define NCOLS 16          // example-columns (16 examples each)
#define NROWBLK 16        // unit-tile blocks per column

typedef __attribute__((ext_vector_type(8))) short short8;   // 8 bf16 (MFMA A/B frag)
typedef __attribute__((ext_vector_type(4))) float f32x4;    // MFMA C/D frag

__device__ __forceinline__ float sig_(float x) {
    return __builtin_amdgcn_rcpf(1.0f + __builtin_amdgcn_exp2f(-1.44269504f * x));
}
__device__ __forceinline__ float tanh_(float x) {
    return 1.0f - 2.0f * __builtin_amdgcn_rcpf(1.0f + __builtin_amdgcn_exp2f(2.88539008f * x));
}

__global__ void zero_flags(int* flags, int n) {
    int i = blockIdx.x * blockDim.x + threadIdx.x;
    if (i < n) flags[i] = 0;
}

// Persistent LSTM, 1-wave blocks, relaxed-atomic sync (R3 protocol, R4 layout).
// 256 blocks = 16 unit-tiles x 16 example-columns. Block b: i=b>>4 -> u0=i*16,
// j=b&15 -> e0=j*16. Lane l: mrow=l&15 -> ex=e0+mrow; kg=l>>4 -> units ub=u0+4*kg..+3.
// Weights in VGPRs. h exchanged as packed bf16 u64 through hbuf (parity double buffer,
// relaxed agent atomics, sc1 -> coherent at IF$); h loaded DIRECTLY into MFMA fragments
// (no LDS round-trip). Only x[t] goes through LDS (staged before the spin).
__global__ __launch_bounds__(64, 1) void lstm_persist(
    const float* __restrict__ X,     // [256,128,512]
    const float* __restrict__ Wih,   // [1024,128]
    const float* __restrict__ Whh,   // [1024,256]
    const float* __restrict__ bias,  // [1024]
    float* __restrict__ A,           // [512,256,256]
    float* __restrict__ C,           // [512,256,256]
    int* __restrict__ flags,         // [512*16]
    unsigned long long* __restrict__ hbuf) // [2][256][64] u64 = 4 bf16 units each
{
    // Ws rows: stride 392 bf16 = 784 B (16B-aligned, bank-spread). One-time staging only.
    __shared__ __align__(16) __hip_bfloat16 Ws[4][16][392]; // 50.2 KB
    __shared__ __align__(16) __hip_bfloat16 Xs[16][136];    // x[t]: [ex_local][128], 4.3 KB

    const int tid = threadIdx.x;
    const int b = blockIdx.x;
    const int i = b >> 4, j = b & 15;
    const int u0 = i * 16, e0 = j * 16;

    // ---- one-time weight staging: fp32 -> bf16 in LDS, [gate][unit_local][k] ----
    for (int idx = tid; idx < 64 * 96; idx += 64) {   // 64 rows x 96 float4 (64 Whh + 32 Wih)
        const int row = idx / 96, q = idx - row * 96;
        const int g = row >> 4, ul = row & 15;
        float4 v;
        int k0;
        if (q < 64) {
            v = *(const float4*)(Whh + (size_t)(g * HDIM + u0 + ul) * HDIM + 4 * q);
            k0 = 4 * q;
        } else {
            v = *(const float4*)(Wih + (size_t)(g * HDIM + u0 + ul) * NIN + 4 * (q - 64));
            k0 = HDIM + 4 * (q - 64);
        }
        Ws[g][ul][k0 + 0] = (__hip_bfloat16)v.x;
        Ws[g][ul][k0 + 1] = (__hip_bfloat16)v.y;
        Ws[g][ul][k0 + 2] = (__hip_bfloat16)v.z;
        Ws[g][ul][k0 + 3] = (__hip_bfloat16)v.w;
    }
    __syncthreads();

    const int mrow = tid & 15;          // frag row; D: col -> ex_local
    const int kg   = tid >> 4;          // k-group; D: rows (kg*4+r) -> unit_local
    const int ex   = e0 + mrow;
    const int ub   = u0 + kg * 4;       // this lane's first unit

    // ---- W fragments -> registers (loop-invariant): 4 gates x 12 k-chunks ----
    short8 wf0[12], wf1[12], wf2[12], wf3[12];
#pragma unroll
    for (int kk = 0; kk < 12; ++kk) {
        wf0[kk] = *(const short8*)&Ws[0][mrow][kk * 32 + kg * 8];
        wf1[kk] = *(const short8*)&Ws[1][mrow][kk * 32 + kg * 8];
        wf2[kk] = *(const short8*)&Ws[2][mrow][kk * 32 + kg * 8];
        wf3[kk] = *(const short8*)&Ws[3][mrow][kk * 32 + kg * 8];
    }
    // ---- bias -> registers: 2*b for my 4 units x 4 gates ----
    float bsr[4][4];
#pragma unroll
    for (int g = 0; g < 4; ++g)
#pragma unroll
        for (int r = 0; r < 4; ++r)
            bsr[g][r] = 2.0f * bias[g * HDIM + ub + r];

    float cr[4] = {0.f, 0.f, 0.f, 0.f};

    for (int t = 0; t < TSTEPS; ++t) {
        // ---- stage x[t] into LDS (recurrence-independent; overlaps other blocks' work) ----
#pragma unroll
        for (int s = 0; s < 32; ++s) {
            const int idx = s * 64 + tid;           // 2048 = 16 ex x 128 inputs
            const int exl = idx >> 7, ii = idx & 127;
            const float xv = X[((size_t)(e0 + exl) * NIN + ii) * TSTEPS + t];
            Xs[exl][ii] = (__hip_bfloat16)xv;
        }

        // ---- wait for h[t-1] (relaxed spin + sleep; R3 protocol) ----
        short8 zh[8];
        if (t > 0) {
            const int* f = &flags[(t - 1) * NCOLS + j];
            while (__hip_atomic_load(f, __ATOMIC_RELAXED, __HIP_MEMORY_SCOPE_AGENT) < NROWBLK) {
                __builtin_amdgcn_s_sleep(2);
            }
            asm volatile("" ::: "memory");   // pin compiler ordering; HW issue is in-order
            // ---- h[t-1] directly into B-fragments: 2 u64 agent loads per k-chunk ----
            const unsigned long long* hb =
                hbuf + (size_t)((t - 1) & 1) * NEX * 64 + (size_t)ex * 64 + kg * 2;
#pragma unroll
            for (int kk = 0; kk < 8; ++kk) {
                union { unsigned long long u[2]; short8 v; } tmp;
                tmp.u[0] = __hip_atomic_load(hb + kk * 8 + 0, __ATOMIC_RELAXED, __HIP_MEMORY_SCOPE_AGENT);
                tmp.u[1] = __hip_atomic_load(hb + kk * 8 + 1, __ATOMIC_RELAXED, __HIP_MEMORY_SCOPE_AGENT);
                zh[kk] = tmp.v;
            }
        } else {
#pragma unroll
            for (int kk = 0; kk < 8; ++kk) zh[kk] = short8{0, 0, 0, 0, 0, 0, 0, 0};
        }

        // ---- gate GEMM: D[16u x 16ex] per gate, K=384 ----
        f32x4 a0 = {0.f, 0.f, 0.f, 0.f}, a1 = a0, a2 = a0, a3 = a0;
#pragma unroll
        for (int kk = 0; kk < 8; ++kk) {            // h part (K=256) from registers
            a0 = __builtin_amdgcn_mfma_f32_16x16x32_bf16(wf0[kk], zh[kk], a0, 0, 0, 0);
            a1 = __builtin_amdgcn_mfma_f32_16x16x32_bf16(wf1[kk], zh[kk], a1, 0, 0, 0);
            a2 = __builtin_amdgcn_mfma_f32_16x16x32_bf16(wf2[kk], zh[kk], a2, 0, 0, 0);
            a3 = __builtin_amdgcn_mfma_f32_16x16x32_bf16(wf3[kk], zh[kk], a3, 0, 0, 0);
        }
#pragma unroll
        for (int kk = 8; kk < 12; ++kk) {           // x part (K=128) from LDS
            const short8 zf = *(const short8*)&Xs[mrow][(kk - 8) * 32 + kg * 8];
            a0 = __builtin_amdgcn_mfma_f32_16x16x32_bf16(wf0[kk], zf, a0, 0, 0, 0);
            a1 = __builtin_amdgcn_mfma_f32_16x16x32_bf16(wf1[kk], zf, a1, 0, 0, 0);
            a2 = __builtin_amdgcn_mfma_f32_16x16x32_bf16(wf2[kk], zf, a2, 0, 0, 0);
            a3 = __builtin_amdgcn_mfma_f32_16x16x32_bf16(wf3[kk], zf, a3, 0, 0, 0);
        }

        // ---- pointwise cell (register-local): r -> unit ub+r, ex fixed ----
        float hr[4];
#pragma unroll
        for (int r = 0; r < 4; ++r) {
            const float gi = sig_(a0[r] + bsr[0][r]);
            const float gf = sig_(a1[r] + bsr[1][r]);
            const float gg = tanh_(a2[r] + bsr[2][r]);
            const float go = sig_(a3[r] + bsr[3][r]);
            cr[r] = gf * cr[r] + gi * gg;
            hr[r] = go * tanh_(cr[r]);
        }

        // ---- publish h first (single u64 agent store), then flag, then bulk A/C ----
        union { __hip_bfloat16 h[4]; unsigned long long u; } P;
        P.h[0] = __float2bfloat16(hr[0]);
        P.h[1] = __float2bfloat16(hr[1]);
        P.h[2] = __float2bfloat16(hr[2]);
        P.h[3] = __float2bfloat16(hr[3]);
        __hip_atomic_store(hbuf + (size_t)(t & 1) * NEX * 64 + (size_t)ex * 64 + (ub >> 2),
                           P.u, __ATOMIC_RELAXED, __HIP_MEMORY_SCOPE_AGENT);

        asm volatile("s_waitcnt vmcnt(0)" ::: "memory");
        if (tid == 0) {
            __hip_atomic_fetch_add(&flags[t * NCOLS + j], 1,
                                   __ATOMIC_RELAXED, __HIP_MEMORY_SCOPE_AGENT);
        }

        // A/C stores off the critical path (plain cached stores)
        const size_t off = (size_t)t * NEX * HDIM + (size_t)ex * HDIM + ub;
        *(float4*)&A[off] = make_float4(hr[0], hr[1], hr[2], hr[3]);
        *(float4*)&C[off] = make_float4(cr[0], cr[1], cr[2], cr[3]);
    }
}

extern "C" void kernel_launch(void* const* d_in, const int* in_sizes, int n_in,
                              void* d_out, int out_size, void* d_ws, size_t ws_size,
                              hipStream_t stream) {
    const float* X   = (const float*)d_in[0];  // [256,128,512]
    const float* Wih = (const float*)d_in[1];  // [1024,128]
    const float* Whh = (const float*)d_in[2];  // [1024,256]
    const float* b   = (const float*)d_in[3];  // [1024]
    float* A = (float*)d_out;                           // [512,256,256]
    float* C = A + (size_t)TSTEPS * NEX * HDIM;         // [512,256,256]

    int* flags = (int*)d_ws;                            // [512*16] ints = 32 KB
    unsigned long long* hbuf =
        (unsigned long long*)((char*)d_ws + (size_t)TSTEPS * NCOLS * sizeof(int));
                                                        // [2][256][64] u64 = 256 KB

    const int nflags = TSTEPS * NCOLS;
    zero_flags<<<(nflags + 255) / 256, 256, 0, stream>>>(flags, nflags);

    void* args[] = {(void*)&X, (void*)&Wih, (void*)&Whh, (void*)&b,
                    (void*)&A, (void*)&C, (void*)&flags, (void*)&hbuf};
    hipError_t err = hipLaunchCooperativeKernel((const void*)lstm_persist,
                                                dim3(256), dim3(64), args, 0, stream);
    if (err != hipSuccess) {
        lstm_persist<<<dim3(256), dim3(64), 0, stream>>>(X, Wih, Whh, b, A, C, flags, hbuf);
    }
}

// Round 6
// 2766.905 us; speedup vs baseline: 3.4590x; 1.3131x over previous
//
#include <hip/hip_runtime.h>
#include <hip/hip_bf16.h>

#define TSTEPS 512
#define NEX 256
#define NIN 128
#define HDIM 256
#define NCOLS 16          // example-columns (16 examples each)
#define NROWBLK 16        // unit-tile blocks per column
#define TAGSTRIDE 16      // u32 per tag slot = 64B (own cache line per producer)

typedef __attribute__((ext_vector_type(8))) short short8;   // 8 bf16 (MFMA A/B frag)
typedef __attribute__((ext_vector_type(4))) float f32x4;    // MFMA C/D frag

__device__ __forceinline__ float sig_(float x) {
    return __builtin_amdgcn_rcpf(1.0f + __builtin_amdgcn_exp2f(-1.44269504f * x));
}
__device__ __forceinline__ float tanh_(float x) {
    return 1.0f - 2.0f * __builtin_amdgcn_rcpf(1.0f + __builtin_amdgcn_exp2f(2.88539008f * x));
}

__global__ void zero_flags(unsigned int* tags, int n) {
    int i = blockIdx.x * blockDim.x + threadIdx.x;
    if (i < n) tags[i] = 0u;
}

// Persistent LSTM, 1-wave blocks. 256 blocks = 16 unit-tiles x 16 example-columns.
// Block b: i=b>>4 -> u0=i*16 (units), j=b&15 -> e0=j*16 (examples). Lane l:
// mrow=l&15 -> ex=e0+mrow (D col); kg=l>>4 -> units ub=u0+4*kg..+3 (D rows).
// Sync: per-producer MONOTONE tag slots (64B apart, value = last published t+1);
// publish = one relaxed agent store (no RMW); poll = lanes 0..15 read 16 tag lines,
// __all(tag >= t). h exchanged as packed-bf16 u64 via hbuf parity double buffer.
// x[t+1] fragments are loaded and pre-multiplied into xacc in the POST-publish
// window, so the post-spin critical path is h-load + 32 MFMA + pointwise + publish.
__global__ __launch_bounds__(64, 1) void lstm_persist(
    const float* __restrict__ X,     // [256,128,512]
    const float* __restrict__ Wih,   // [1024,128]
    const float* __restrict__ Whh,   // [1024,256]
    const float* __restrict__ bias,  // [1024]
    float* __restrict__ A,           // [512,256,256]
    float* __restrict__ C,           // [512,256,256]
    unsigned int* __restrict__ tags, // [16 cols][16 rowblk][TAGSTRIDE]
    unsigned long long* __restrict__ hbuf) // [2][256][64] u64 = 4 bf16 units each
{
    // Ws rows: stride 392 bf16 = 784 B (16B-aligned, bank-spread). One-time staging only.
    __shared__ __align__(16) __hip_bfloat16 Ws[4][16][392]; // 50.2 KB

    const int tid = threadIdx.x;
    const int b = blockIdx.x;
    const int i = b >> 4, j = b & 15;
    const int u0 = i * 16, e0 = j * 16;

    // ---- one-time weight staging: fp32 -> bf16 in LDS, [gate][unit_local][k] ----
    for (int idx = tid; idx < 64 * 96; idx += 64) {   // 64 rows x 96 float4 (64 Whh + 32 Wih)
        const int row = idx / 96, q = idx - row * 96;
        const int g = row >> 4, ul = row & 15;
        float4 v;
        int k0;
        if (q < 64) {
            v = *(const float4*)(Whh + (size_t)(g * HDIM + u0 + ul) * HDIM + 4 * q);
            k0 = 4 * q;
        } else {
            v = *(const float4*)(Wih + (size_t)(g * HDIM + u0 + ul) * NIN + 4 * (q - 64));
            k0 = HDIM + 4 * (q - 64);
        }
        Ws[g][ul][k0 + 0] = (__hip_bfloat16)v.x;
        Ws[g][ul][k0 + 1] = (__hip_bfloat16)v.y;
        Ws[g][ul][k0 + 2] = (__hip_bfloat16)v.z;
        Ws[g][ul][k0 + 3] = (__hip_bfloat16)v.w;
    }
    __syncthreads();

    const int mrow = tid & 15;          // D col -> ex_local
    const int kg   = tid >> 4;          // D rows (kg*4+r) -> unit_local
    const int ex   = e0 + mrow;
    const int ub   = u0 + kg * 4;       // this lane's first unit

    // ---- W fragments -> registers (loop-invariant): 4 gates x 12 k-chunks ----
    short8 wf0[12], wf1[12], wf2[12], wf3[12];
#pragma unroll
    for (int kk = 0; kk < 12; ++kk) {
        wf0[kk] = *(const short8*)&Ws[0][mrow][kk * 32 + kg * 8];
        wf1[kk] = *(const short8*)&Ws[1][mrow][kk * 32 + kg * 8];
        wf2[kk] = *(const short8*)&Ws[2][mrow][kk * 32 + kg * 8];
        wf3[kk] = *(const short8*)&Ws[3][mrow][kk * 32 + kg * 8];
    }
    float bsr[4][4];
#pragma unroll
    for (int g = 0; g < 4; ++g)
#pragma unroll
        for (int r = 0; r < 4; ++r)
            bsr[g][r] = 2.0f * bias[g * HDIM + ub + r];

    const f32x4 Z4 = {0.f, 0.f, 0.f, 0.f};
    float cr[4] = {0.f, 0.f, 0.f, 0.f};
    f32x4 xa0, xa1, xa2, xa3;

    const unsigned int* tagbase = tags + (size_t)j * NROWBLK * TAGSTRIDE;
    unsigned int* tagself = tags + ((size_t)j * NROWBLK + i) * TAGSTRIDE;

    // x-window: load x(tt) fragments direct global->reg, pre-multiply into xacc.
#define X_WINDOW(tt)                                                               \
    {                                                                              \
        const float* xb = X + (size_t)(e0 + mrow) * NIN * TSTEPS + (tt);           \
        xa0 = Z4; xa1 = Z4; xa2 = Z4; xa3 = Z4;                                    \
        _Pragma("unroll")                                                          \
        for (int kk = 0; kk < 4; ++kk) {                                           \
            union { __hip_bfloat16 hh[8]; short8 v; } ux;                          \
            _Pragma("unroll")                                                      \
            for (int e = 0; e < 8; ++e) {                                          \
                const int ii = kk * 32 + kg * 8 + e;                               \
                ux.hh[e] = (__hip_bfloat16)xb[(size_t)ii * TSTEPS];                \
            }                                                                      \
            xa0 = __builtin_amdgcn_mfma_f32_16x16x32_bf16(wf0[8 + kk], ux.v, xa0, 0, 0, 0); \
            xa1 = __builtin_amdgcn_mfma_f32_16x16x32_bf16(wf1[8 + kk], ux.v, xa1, 0, 0, 0); \
            xa2 = __builtin_amdgcn_mfma_f32_16x16x32_bf16(wf2[8 + kk], ux.v, xa2, 0, 0, 0); \
            xa3 = __builtin_amdgcn_mfma_f32_16x16x32_bf16(wf3[8 + kk], ux.v, xa3, 0, 0, 0); \
        }                                                                          \
    }

    X_WINDOW(0);   // prologue: xacc for t=0

    for (int t = 0; t < TSTEPS; ++t) {
        f32x4 a0 = xa0, a1 = xa1, a2 = xa2, a3 = xa3;

        if (t > 0) {
            // ---- poll: lanes 0..15 each watch one producer's tag line ----
            int ready;
            do {
                int v = 0x7fffffff;
                if (tid < NROWBLK)
                    v = (int)__hip_atomic_load(tagbase + tid * TAGSTRIDE,
                                               __ATOMIC_RELAXED, __HIP_MEMORY_SCOPE_AGENT);
                ready = __all(v >= t);
            } while (!ready);
            asm volatile("" ::: "memory");   // pin compiler ordering; HW issue is in-order

            // ---- h[t-1] directly into B-fragments, then 32 h-part MFMAs ----
            const unsigned long long* hb =
                hbuf + (size_t)((t - 1) & 1) * NEX * 64 + (size_t)ex * 64 + kg * 2;
            short8 zh[8];
#pragma unroll
            for (int kk = 0; kk < 8; ++kk) {
                union { unsigned long long u[2]; short8 v; } tmp;
                tmp.u[0] = __hip_atomic_load(hb + kk * 8 + 0, __ATOMIC_RELAXED, __HIP_MEMORY_SCOPE_AGENT);
                tmp.u[1] = __hip_atomic_load(hb + kk * 8 + 1, __ATOMIC_RELAXED, __HIP_MEMORY_SCOPE_AGENT);
                zh[kk] = tmp.v;
            }
#pragma unroll
            for (int kk = 0; kk < 8; ++kk) {
                a0 = __builtin_amdgcn_mfma_f32_16x16x32_bf16(wf0[kk], zh[kk], a0, 0, 0, 0);
                a1 = __builtin_amdgcn_mfma_f32_16x16x32_bf16(wf1[kk], zh[kk], a1, 0, 0, 0);
                a2 = __builtin_amdgcn_mfma_f32_16x16x32_bf16(wf2[kk], zh[kk], a2, 0, 0, 0);
                a3 = __builtin_amdgcn_mfma_f32_16x16x32_bf16(wf3[kk], zh[kk], a3, 0, 0, 0);
            }
        }

        // ---- pointwise cell (register-local): r -> unit ub+r, ex fixed ----
        float hr[4];
#pragma unroll
        for (int r = 0; r < 4; ++r) {
            const float gi = sig_(a0[r] + bsr[0][r]);
            const float gf = sig_(a1[r] + bsr[1][r]);
            const float gg = tanh_(a2[r] + bsr[2][r]);
            const float go = sig_(a3[r] + bsr[3][r]);
            cr[r] = gf * cr[r] + gi * gg;
            hr[r] = go * tanh_(cr[r]);
        }

        // ---- publish h (one u64 agent store), drain, then tag (one plain store) ----
        union { __hip_bfloat16 h[4]; unsigned long long u; } P;
        P.h[0] = __float2bfloat16(hr[0]);
        P.h[1] = __float2bfloat16(hr[1]);
        P.h[2] = __float2bfloat16(hr[2]);
        P.h[3] = __float2bfloat16(hr[3]);
        __hip_atomic_store(hbuf + (size_t)(t & 1) * NEX * 64 + (size_t)ex * 64 + (ub >> 2),
                           P.u, __ATOMIC_RELAXED, __HIP_MEMORY_SCOPE_AGENT);
        asm volatile("s_waitcnt vmcnt(0)" ::: "memory");
        if (tid == 0) {
            __hip_atomic_store(tagself, (unsigned int)(t + 1),
                               __ATOMIC_RELAXED, __HIP_MEMORY_SCOPE_AGENT);
        }

        // ---- off critical path: outputs + next-step x window ----
        const size_t off = (size_t)t * NEX * HDIM + (size_t)ex * HDIM + ub;
        *(float4*)&A[off] = make_float4(hr[0], hr[1], hr[2], hr[3]);
        *(float4*)&C[off] = make_float4(cr[0], cr[1], cr[2], cr[3]);

        if (t + 1 < TSTEPS) {
            X_WINDOW(t + 1);
        }
    }
#undef X_WINDOW
}

extern "C" void kernel_launch(void* const* d_in, const int* in_sizes, int n_in,
                              void* d_out, int out_size, void* d_ws, size_t ws_size,
                              hipStream_t stream) {
    const float* X   = (const float*)d_in[0];  // [256,128,512]
    const float* Wih = (const float*)d_in[1];  // [1024,128]
    const float* Whh = (const float*)d_in[2];  // [1024,256]
    const float* b   = (const float*)d_in[3];  // [1024]
    float* A = (float*)d_out;                           // [512,256,256]
    float* C = A + (size_t)TSTEPS * NEX * HDIM;         // [512,256,256]

    unsigned int* tags = (unsigned int*)d_ws;           // 256 slots x 64B = 16 KB
    unsigned long long* hbuf =
        (unsigned long long*)((char*)d_ws + (size_t)NCOLS * NROWBLK * TAGSTRIDE * sizeof(unsigned int));
                                                        // [2][256][64] u64 = 256 KB

    const int ntags = NCOLS * NROWBLK * TAGSTRIDE;
    zero_flags<<<(ntags + 255) / 256, 256, 0, stream>>>(tags, ntags);

    void* args[] = {(void*)&X, (void*)&Wih, (void*)&Whh, (void*)&b,
                    (void*)&A, (void*)&C, (void*)&tags, (void*)&hbuf};
    hipError_t err = hipLaunchCooperativeKernel((const void*)lstm_persist,
                                                dim3(256), dim3(64), args, 0, stream);
    if (err != hipSuccess) {
        lstm_persist<<<dim3(256), dim3(64), 0, stream>>>(X, Wih, Whh, b, A, C, tags, hbuf);
    }
}